// Round 1
// baseline (7854.562 us; speedup 1.0000x reference)
//
#include <hip/hip_runtime.h>
#include <cstddef>

#define Bn 8
#define Sn 2048
#define Dn 512
#define Ln 4
#define Hn 8
#define Mn 2048
#define EPSc 1e-3f

typedef __bf16 bf16x8 __attribute__((ext_vector_type(8)));
typedef float f32x4 __attribute__((ext_vector_type(4)));
typedef unsigned short us8v __attribute__((ext_vector_type(8)));
typedef unsigned short us4v __attribute__((ext_vector_type(4)));

static __device__ __forceinline__ unsigned short f2bf(float f) {
  unsigned int u = __builtin_bit_cast(unsigned int, f);
  u = u + 0x7fffu + ((u >> 16) & 1u);
  return (unsigned short)(u >> 16);
}

static __device__ __forceinline__ f32x4 mfma_bf16(bf16x8 a, bf16x8 b, f32x4 c) {
  return __builtin_amdgcn_mfma_f32_16x16x32_bf16(a, b, c, 0, 0, 0);
}

// in: f32 [Z][R][C] -> out: bf16 [Z][C][R]   (R,C multiples of 32)
__global__ void transpose_convert(const float* __restrict__ in, unsigned short* __restrict__ outT,
                                  int R, int C) {
  __shared__ float tile[32][33];
  size_t zoff = (size_t)blockIdx.z * R * C;
  in += zoff; outT += zoff;
  int c0 = blockIdx.x * 32, r0 = blockIdx.y * 32;
  for (int i = threadIdx.y; i < 32; i += 8)
    tile[i][threadIdx.x] = in[(size_t)(r0 + i) * C + c0 + threadIdx.x];
  __syncthreads();
  for (int i = threadIdx.y; i < 32; i += 8)
    outT[(size_t)(c0 + i) * R + r0 + threadIdx.x] = f2bf(tile[threadIdx.x][i]);
}

// Hcat = [cache | ht], Qcat = [cache | g]  (bf16, row stride 2D)
__global__ void concat_kernel(const float* __restrict__ c, const float* __restrict__ ht,
                              const float* __restrict__ gq,
                              unsigned short* __restrict__ Hc, unsigned short* __restrict__ Qc) {
  int idx = blockIdx.x * 256 + threadIdx.x;   // over Sn * (Dn/4)
  int s = idx >> 7;
  int c4 = (idx & 127) << 2;
  float4 vc = *(const float4*)(c + (size_t)s * Dn + c4);
  float4 vh = *(const float4*)(ht + (size_t)s * Dn + c4);
  float4 vg = *(const float4*)(gq + (size_t)s * Dn + c4);
  us4v pc = {f2bf(vc.x), f2bf(vc.y), f2bf(vc.z), f2bf(vc.w)};
  us4v ph = {f2bf(vh.x), f2bf(vh.y), f2bf(vh.z), f2bf(vh.w)};
  us4v pg = {f2bf(vg.x), f2bf(vg.y), f2bf(vg.z), f2bf(vg.w)};
  *(us4v*)(Hc + (size_t)s * (2 * Dn) + c4) = pc;
  *(us4v*)(Hc + (size_t)s * (2 * Dn) + Dn + c4) = ph;
  *(us4v*)(Qc + (size_t)s * (2 * Dn) + c4) = pc;
  *(us4v*)(Qc + (size_t)s * (2 * Dn) + Dn + c4) = pg;
}

// C[M=2048][N] = A[2048][K] @ Bt[N][K]^T + bias;  128x128 tile, BK=32, 4 waves
template<int RELU>
__global__ __launch_bounds__(256) void gemm_kernel(const unsigned short* __restrict__ A,
                                                   const unsigned short* __restrict__ Bt,
                                                   const float* __restrict__ bias,
                                                   float* __restrict__ Cf,
                                                   unsigned short* __restrict__ Cb,
                                                   int N, int K) {
  __shared__ __align__(16) unsigned short As[128][40];
  __shared__ __align__(16) unsigned short Bs[128][40];
  const int tid = threadIdx.x;
  const int lane = tid & 63, w = tid >> 6;
  const int m0 = blockIdx.y * 128, n0 = blockIdx.x * 128;
  const int wrow = (w >> 1) * 64, wcol = (w & 1) * 64;
  const int lr = lane & 15, lg = lane >> 4;
  f32x4 acc[4][4] = {};
  for (int kt = 0; kt < K; kt += 32) {
    __syncthreads();
#pragma unroll
    for (int half = 0; half < 2; ++half) {
      int i = tid + half * 256;
      int r = i >> 2, kc = (i & 3) << 3;
      *(uint4*)&As[r][kc] = *(const uint4*)(A + (size_t)(m0 + r) * K + kt + kc);
      *(uint4*)&Bs[r][kc] = *(const uint4*)(Bt + (size_t)(n0 + r) * K + kt + kc);
    }
    __syncthreads();
    bf16x8 af[4];
#pragma unroll
    for (int mi = 0; mi < 4; ++mi)
      af[mi] = *(const bf16x8*)&As[wrow + mi * 16 + lr][lg * 8];
#pragma unroll
    for (int ni = 0; ni < 4; ++ni) {
      bf16x8 bfr = *(const bf16x8*)&Bs[wcol + ni * 16 + lr][lg * 8];
#pragma unroll
      for (int mi = 0; mi < 4; ++mi)
        acc[mi][ni] = mfma_bf16(af[mi], bfr, acc[mi][ni]);
    }
  }
#pragma unroll
  for (int mi = 0; mi < 4; ++mi)
#pragma unroll
    for (int ni = 0; ni < 4; ++ni) {
      int col = n0 + wcol + ni * 16 + lr;
      float bv = bias[col];
#pragma unroll
      for (int r = 0; r < 4; ++r) {
        int row = m0 + wrow + mi * 16 + lg * 4 + r;
        float v = acc[mi][ni][r] + bv;
        if (RELU) v = fmaxf(v, 0.f);
        if (Cf) Cf[(size_t)row * N + col] = v;
        if (Cb) Cb[(size_t)row * N + col] = f2bf(v);
      }
    }
}

// Flash attention: block = (q-tile of 64, head). 4 waves, each 16 q-rows.
__global__ __launch_bounds__(256) void attn_kernel(const unsigned short* __restrict__ Qb,
                                                   const unsigned short* __restrict__ Kb,
                                                   const unsigned short* __restrict__ Vb,
                                                   unsigned short* __restrict__ Oa) {
  __shared__ __align__(16) unsigned short Ks[64][72];
  __shared__ __align__(16) unsigned short VT[64][72];
  __shared__ __align__(16) unsigned short Pl[4][16][72];
  const int tid = threadIdx.x, lane = tid & 63, w = tid >> 6;
  const int lr = lane & 15, lg = lane >> 4;
  const int h = blockIdx.y;
  const int q0 = blockIdx.x * 64;
  const int qrow = q0 + w * 16 + lr;
  bf16x8 aq0 = *(const bf16x8*)(Qb + (size_t)qrow * Dn + h * 64 + lg * 8);
  bf16x8 aq1 = *(const bf16x8*)(Qb + (size_t)qrow * Dn + h * 64 + 32 + lg * 8);
  f32x4 o[4] = {};
  float mrow[4] = {-3e38f, -3e38f, -3e38f, -3e38f};
  float lrow[4] = {0.f, 0.f, 0.f, 0.f};
  for (int kt = 0; kt < Sn; kt += 64) {
    __syncthreads();
#pragma unroll
    for (int half = 0; half < 2; ++half) {
      int i = tid + half * 256;
      int key = i >> 3, d0 = (i & 7) << 3;
      *(uint4*)&Ks[key][d0] = *(const uint4*)(Kb + (size_t)(kt + key) * Dn + h * 64 + d0);
      uint4 uv = *(const uint4*)(Vb + (size_t)(kt + key) * Dn + h * 64 + d0);
      us8v v8 = __builtin_bit_cast(us8v, uv);
#pragma unroll
      for (int j = 0; j < 8; ++j) VT[d0 + j][key] = v8[j];
    }
    __syncthreads();
    f32x4 s[4];
#pragma unroll
    for (int nb = 0; nb < 4; ++nb) {
      bf16x8 bk0 = *(const bf16x8*)&Ks[lr + 16 * nb][lg * 8];
      bf16x8 bk1 = *(const bf16x8*)&Ks[lr + 16 * nb][32 + lg * 8];
      f32x4 z = {};
      z = mfma_bf16(aq0, bk0, z);
      z = mfma_bf16(aq1, bk1, z);
      s[nb] = z;
    }
#pragma unroll
    for (int r = 0; r < 4; ++r) {
      float mx = -3e38f;
#pragma unroll
      for (int nb = 0; nb < 4; ++nb) { s[nb][r] *= 0.125f; mx = fmaxf(mx, s[nb][r]); }
      mx = fmaxf(mx, __shfl_xor(mx, 1));
      mx = fmaxf(mx, __shfl_xor(mx, 2));
      mx = fmaxf(mx, __shfl_xor(mx, 4));
      mx = fmaxf(mx, __shfl_xor(mx, 8));
      float mnew = fmaxf(mrow[r], mx);
      float resc = __expf(mrow[r] - mnew);
      float ps = 0.f;
#pragma unroll
      for (int nb = 0; nb < 4; ++nb) { float p = __expf(s[nb][r] - mnew); s[nb][r] = p; ps += p; }
      ps += __shfl_xor(ps, 1);
      ps += __shfl_xor(ps, 2);
      ps += __shfl_xor(ps, 4);
      ps += __shfl_xor(ps, 8);
      lrow[r] = lrow[r] * resc + ps;
      mrow[r] = mnew;
#pragma unroll
      for (int nb = 0; nb < 4; ++nb) o[nb][r] *= resc;
    }
#pragma unroll
    for (int nb = 0; nb < 4; ++nb)
#pragma unroll
      for (int r = 0; r < 4; ++r)
        Pl[w][lg * 4 + r][lr + 16 * nb] = f2bf(s[nb][r]);
    __syncthreads();
    bf16x8 ap0 = *(const bf16x8*)&Pl[w][lr][lg * 8];
    bf16x8 ap1 = *(const bf16x8*)&Pl[w][lr][32 + lg * 8];
#pragma unroll
    for (int nb = 0; nb < 4; ++nb) {
      bf16x8 bv0 = *(const bf16x8*)&VT[lr + 16 * nb][lg * 8];
      bf16x8 bv1 = *(const bf16x8*)&VT[lr + 16 * nb][32 + lg * 8];
      o[nb] = mfma_bf16(ap0, bv0, o[nb]);
      o[nb] = mfma_bf16(ap1, bv1, o[nb]);
    }
  }
#pragma unroll
  for (int nb = 0; nb < 4; ++nb)
#pragma unroll
    for (int r = 0; r < 4; ++r) {
      int row = q0 + w * 16 + lg * 4 + r;
      int col = h * 64 + lr + 16 * nb;
      Oa[(size_t)row * Dn + col] = f2bf(o[nb][r] / lrow[r]);
    }
}

// y = gamma * norm(a+b) + beta ; writes up to 3 f32 dests + optional bf16 dest
__global__ __launch_bounds__(256) void ln_kernel(const float* __restrict__ a, const float* __restrict__ b,
                                                 const float* __restrict__ gam, const float* __restrict__ bet,
                                                 float* __restrict__ o1, float* __restrict__ o2,
                                                 float* __restrict__ o3, unsigned short* __restrict__ ob) {
  const int w = threadIdx.x >> 6, lane = threadIdx.x & 63;
  const int row = blockIdx.x * 4 + w;
  const size_t base = (size_t)row * Dn + lane * 8;
  float x[8];
  {
    float4 a0 = *(const float4*)(a + base);
    float4 a1 = *(const float4*)(a + base + 4);
    float4 b0 = *(const float4*)(b + base);
    float4 b1 = *(const float4*)(b + base + 4);
    x[0] = a0.x + b0.x; x[1] = a0.y + b0.y; x[2] = a0.z + b0.z; x[3] = a0.w + b0.w;
    x[4] = a1.x + b1.x; x[5] = a1.y + b1.y; x[6] = a1.z + b1.z; x[7] = a1.w + b1.w;
  }
  float sm = 0.f;
#pragma unroll
  for (int j = 0; j < 8; ++j) sm += x[j];
#pragma unroll
  for (int msk = 1; msk < 64; msk <<= 1) sm += __shfl_xor(sm, msk);
  float mean = sm * (1.f / Dn);
  float vs = 0.f;
#pragma unroll
  for (int j = 0; j < 8; ++j) { float d = x[j] - mean; vs += d * d; }
#pragma unroll
  for (int msk = 1; msk < 64; msk <<= 1) vs += __shfl_xor(vs, msk);
  float rs = rsqrtf(vs * (1.f / Dn) + EPSc);
  float y[8];
  const int col0 = lane * 8;
#pragma unroll
  for (int j = 0; j < 8; ++j)
    y[j] = gam[col0 + j] * ((x[j] - mean) * rs) + bet[col0 + j];
  float4 y0 = make_float4(y[0], y[1], y[2], y[3]);
  float4 y1 = make_float4(y[4], y[5], y[6], y[7]);
  if (o1) { *(float4*)(o1 + base) = y0; *(float4*)(o1 + base + 4) = y1; }
  if (o2) { *(float4*)(o2 + base) = y0; *(float4*)(o2 + base + 4) = y1; }
  if (o3) { *(float4*)(o3 + base) = y0; *(float4*)(o3 + base + 4) = y1; }
  if (ob) {
    us8v p = {f2bf(y[0]), f2bf(y[1]), f2bf(y[2]), f2bf(y[3]),
              f2bf(y[4]), f2bf(y[5]), f2bf(y[6]), f2bf(y[7])};
    *(us8v*)(ob + base) = p;
  }
}

extern "C" void kernel_launch(void* const* d_in, const int* in_sizes, int n_in,
                              void* d_out, int out_size, void* d_ws, size_t ws_size,
                              hipStream_t stream) {
  (void)in_sizes; (void)n_in; (void)out_size; (void)ws_size;
  const float* x   = (const float*)d_in[0];
  const float* gq  = (const float*)d_in[1];
  const float* WQw = (const float*)d_in[2];
  const float* WQb = (const float*)d_in[3];
  const float* WKw = (const float*)d_in[4];
  const float* WKb = (const float*)d_in[5];
  const float* WVw = (const float*)d_in[6];
  const float* WVb = (const float*)d_in[7];
  const float* WOw = (const float*)d_in[8];
  const float* WOb = (const float*)d_in[9];
  const float* l1g = (const float*)d_in[10];
  const float* l1b = (const float*)d_in[11];
  const float* W1  = (const float*)d_in[12];
  const float* b1  = (const float*)d_in[13];
  const float* W2  = (const float*)d_in[14];
  const float* b2  = (const float*)d_in[15];
  const float* l2g = (const float*)d_in[16];
  const float* l2b = (const float*)d_in[17];
  float* out = (float*)d_out;

  char* wsp = (char*)d_ws;
  size_t off = 0;
  auto alloc = [&](size_t bytes) -> void* {
    void* p = wsp + off;
    off += (bytes + 255) & ~(size_t)255;
    return p;
  };

  float* cache = (float*)alloc((size_t)Ln * Sn * Dn * 4);
  float* htb   = (float*)alloc((size_t)Sn * Dn * 4);
  unsigned short* Hcat = (unsigned short*)alloc((size_t)Sn * 2 * Dn * 2);
  unsigned short* Qcat = (unsigned short*)alloc((size_t)Sn * 2 * Dn * 2);
  float* Qf = (float*)alloc((size_t)Sn * Dn * 4);
  unsigned short* Qb2 = (unsigned short*)alloc((size_t)Sn * Dn * 2);
  unsigned short* Kb2 = (unsigned short*)alloc((size_t)Sn * Dn * 2);
  unsigned short* Vb2 = (unsigned short*)alloc((size_t)Sn * Dn * 2);
  float* O2 = (float*)alloc((size_t)Sn * Dn * 4);
  float* yf = (float*)alloc((size_t)Sn * Dn * 4);
  unsigned short* yb = (unsigned short*)alloc((size_t)Sn * Dn * 2);
  float* f2 = (float*)alloc((size_t)Sn * Dn * 4);
  unsigned short* WQt = (unsigned short*)alloc((size_t)Ln * 2 * Dn * Dn * 2);
  unsigned short* WKt = (unsigned short*)alloc((size_t)Ln * 2 * Dn * Dn * 2);
  unsigned short* WVt = (unsigned short*)alloc((size_t)Ln * 2 * Dn * Dn * 2);
  unsigned short* WOt = (unsigned short*)alloc((size_t)Ln * Dn * Dn * 2);
  unsigned short* W1t = (unsigned short*)alloc((size_t)Ln * Dn * Mn * 2);
  unsigned short* W2t = (unsigned short*)alloc((size_t)Ln * Mn * Dn * 2);
  // lifetime-disjoint aliases (Hcat/Qcat are dead after the V GEMM):
  unsigned short* Oa = Hcat;   // [Sn][Dn] bf16, written by attn, read by WO GEMM
  unsigned short* f1 = Hcat;   // [Sn][Mn] bf16, spans Hcat+Qcat (contiguous)

  hipMemsetAsync(cache, 0, (size_t)Ln * Sn * Dn * 4, stream);

  dim3 tb(32, 8);
  transpose_convert<<<dim3(Dn / 32, 2 * Dn / 32, Ln), tb, 0, stream>>>(WQw, WQt, 2 * Dn, Dn);
  transpose_convert<<<dim3(Dn / 32, 2 * Dn / 32, Ln), tb, 0, stream>>>(WKw, WKt, 2 * Dn, Dn);
  transpose_convert<<<dim3(Dn / 32, 2 * Dn / 32, Ln), tb, 0, stream>>>(WVw, WVt, 2 * Dn, Dn);
  transpose_convert<<<dim3(Dn / 32, Dn / 32, Ln), tb, 0, stream>>>(WOw, WOt, Dn, Dn);
  transpose_convert<<<dim3(Mn / 32, Dn / 32, Ln), tb, 0, stream>>>(W1, W1t, Dn, Mn);
  transpose_convert<<<dim3(Dn / 32, Mn / 32, Ln), tb, 0, stream>>>(W2, W2t, Mn, Dn);

  for (int b = 0; b < Bn; ++b) {
    for (int i = 0; i < Ln; ++i) {
      const float* ht_src = (i == 0) ? (x + (size_t)b * Sn * Dn) : htb;
      concat_kernel<<<Sn * Dn / 4 / 256, 256, 0, stream>>>(
          cache + (size_t)i * Sn * Dn, ht_src, gq + (size_t)b * Sn * Dn, Hcat, Qcat);
      gemm_kernel<0><<<dim3(Dn / 128, Sn / 128), 256, 0, stream>>>(
          Qcat, WQt + (size_t)i * 2 * Dn * Dn, WQb + i * Dn, Qf, Qb2, Dn, 2 * Dn);
      gemm_kernel<0><<<dim3(Dn / 128, Sn / 128), 256, 0, stream>>>(
          Hcat, WKt + (size_t)i * 2 * Dn * Dn, WKb + i * Dn, nullptr, Kb2, Dn, 2 * Dn);
      gemm_kernel<0><<<dim3(Dn / 128, Sn / 128), 256, 0, stream>>>(
          Hcat, WVt + (size_t)i * 2 * Dn * Dn, WVb + i * Dn, nullptr, Vb2, Dn, 2 * Dn);
      attn_kernel<<<dim3(Sn / 64, Hn), 256, 0, stream>>>(Qb2, Kb2, Vb2, Oa);
      gemm_kernel<0><<<dim3(Dn / 128, Sn / 128), 256, 0, stream>>>(
          Oa, WOt + (size_t)i * Dn * Dn, WOb + i * Dn, O2, nullptr, Dn, Dn);
      ln_kernel<<<Sn / 4, 256, 0, stream>>>(O2, Qf, l1g + i * Dn, l1b + i * Dn,
                                            yf, nullptr, nullptr, yb);
      gemm_kernel<1><<<dim3(Mn / 128, Sn / 128), 256, 0, stream>>>(
          yb, W1t + (size_t)i * Dn * Mn, b1 + i * Mn, nullptr, f1, Mn, Dn);
      gemm_kernel<0><<<dim3(Dn / 128, Sn / 128), 256, 0, stream>>>(
          f1, W2t + (size_t)i * Mn * Dn, b2 + i * Dn, f2, nullptr, Dn, Mn);
      ln_kernel<<<Sn / 4, 256, 0, stream>>>(yf, f2, l2g + i * Dn, l2b + i * Dn,
                                            htb, cache + (size_t)i * Sn * Dn,
                                            (i == Ln - 1) ? (out + (size_t)b * Sn * Dn) : nullptr,
                                            nullptr);
    }
  }
}

// Round 2
// 3075.977 us; speedup vs baseline: 2.5535x; 2.5535x over previous
//
#include <hip/hip_runtime.h>
#include <cstddef>

#define Bn 8
#define Sn 2048
#define Dn 512
#define Ln 4
#define Hn 8
#define Mn 2048
#define EPSc 1e-3f
static const size_t SD = (size_t)Sn * Dn;
static const size_t SM = (size_t)Sn * Mn;

typedef __bf16 bf16x8 __attribute__((ext_vector_type(8)));
typedef float f32x4 __attribute__((ext_vector_type(4)));
typedef unsigned short us8v __attribute__((ext_vector_type(8)));
typedef unsigned int u32;

static __device__ __forceinline__ unsigned short f2bf(float f) {
  u32 u = __builtin_bit_cast(u32, f);
  u = u + 0x7fffu + ((u >> 16) & 1u);
  return (unsigned short)(u >> 16);
}
static __device__ __forceinline__ float bf2f(unsigned short u) {
  return __builtin_bit_cast(float, (u32)u << 16);
}
static __device__ __forceinline__ f32x4 mfma_bf16(bf16x8 a, bf16x8 b, f32x4 c) {
  return __builtin_amdgcn_mfma_f32_16x16x32_bf16(a, b, c, 0, 0, 0);
}
static __device__ __forceinline__ int zsel(int4 v, int z) {
  return z == 0 ? v.x : z == 1 ? v.y : z == 2 ? v.z : v.w;
}
static __device__ __forceinline__ void gload16(const unsigned short* g, unsigned short* l) {
  __builtin_amdgcn_global_load_lds((const __attribute__((address_space(1))) u32*)(const void*)g,
                                   (__attribute__((address_space(3))) u32*)(void*)l, 16, 0, 0);
}

// Stage a 128x64 bf16 tile: linear LDS dest, inverse-swizzled global source.
// LDS chunk (row, cc) receives global column-chunk cc^(row&7).  (16B chunks)
static __device__ __forceinline__ void stage_tile(const unsigned short* __restrict__ src, int lda,
                                                  int row0, int col0,
                                                  unsigned short* lds, int w, int lane) {
#pragma unroll
  for (int r = 0; r < 4; ++r) {
    int c = (w * 4 + r) * 64 + lane;
    int row = c >> 3, cc = c & 7;
    int scc = cc ^ (row & 7);
    gload16(src + (size_t)(row0 + row) * lda + col0 + scc * 8, lds + (w * 4 + r) * 64 * 8);
  }
}

// Swizzled fragment reads + 32 MFMAs for one 128x128x64 step.
static __device__ __forceinline__ void gemm_compute_tile(const unsigned short* As, const unsigned short* Bs,
                                                         int wrow, int wcol, int lr, int lg,
                                                         f32x4 acc[4][4]) {
#pragma unroll
  for (int kk = 0; kk < 2; ++kk) {
    bf16x8 af[4], bfr[4];
#pragma unroll
    for (int mi = 0; mi < 4; ++mi) {
      int ra = wrow + mi * 16 + lr;
      af[mi] = *(const bf16x8*)&As[ra * 64 + ((kk * 4 + lg) ^ (ra & 7)) * 8];
      int rb = wcol + mi * 16 + lr;
      bfr[mi] = *(const bf16x8*)&Bs[rb * 64 + ((kk * 4 + lg) ^ (rb & 7)) * 8];
    }
#pragma unroll
    for (int ni = 0; ni < 4; ++ni)
#pragma unroll
      for (int mi = 0; mi < 4; ++mi)
        acc[mi][ni] = mfma_bf16(af[mi], bfr[ni], acc[mi][ni]);
  }
}

// in: f32 [Z][R][C] -> out: bf16 [Z][C][R]
__global__ void transpose_convert(const float* __restrict__ in, unsigned short* __restrict__ outT,
                                  int R, int C, size_t inZ, size_t outZ) {
  __shared__ float tile[32][33];
  in += (size_t)blockIdx.z * inZ;
  outT += (size_t)blockIdx.z * outZ;
  int c0 = blockIdx.x * 32, r0 = blockIdx.y * 32;
  for (int i = threadIdx.y; i < 32; i += 8)
    tile[i][threadIdx.x] = in[(size_t)(r0 + i) * C + c0 + threadIdx.x];
  __syncthreads();
  for (int i = threadIdx.y; i < 32; i += 8)
    outT[(size_t)(c0 + i) * R + r0 + threadIdx.x] = f2bf(tile[threadIdx.x][i]);
}

__global__ void cvt_bf16(const float* __restrict__ in, unsigned short* __restrict__ out) {
  size_t idx = ((size_t)blockIdx.x * 256 + threadIdx.x) * 8;
  float4 a = *(const float4*)(in + idx);
  float4 b = *(const float4*)(in + idx + 4);
  us8v p = {f2bf(a.x), f2bf(a.y), f2bf(a.z), f2bf(a.w), f2bf(b.x), f2bf(b.y), f2bf(b.z), f2bf(b.w)};
  *(us8v*)(out + idx) = p;
}

__global__ void fuse_bias(const float* __restrict__ q, const float* __restrict__ k,
                          const float* __restrict__ v, float* __restrict__ o) {
  int t = blockIdx.x * 256 + threadIdx.x;  // over Ln*1536
  int l = t / 1536, n = t % 1536;
  float val = n < 512 ? q[l * 512 + n] : n < 1024 ? k[l * 512 + n - 512] : v[l * 512 + n - 1024];
  o[t] = val;
}

// Fused QKV GEMM: C[2048][1536] over K=1024 (concat inputs selected per K-tile).
__global__ __launch_bounds__(256) void gemm_qkv(
    const unsigned short* __restrict__ cacheB, const unsigned short* __restrict__ xB,
    const unsigned short* __restrict__ gB,
    const unsigned short* __restrict__ Wt, const float* __restrict__ bias,
    unsigned short* __restrict__ Qb2, float* __restrict__ Qf,
    unsigned short* __restrict__ Kb2, unsigned short* __restrict__ Vb2,
    int4 iz, int4 bz) {
  __shared__ __align__(16) unsigned short As[128 * 64];
  __shared__ __align__(16) unsigned short Bs[128 * 64];
  const int z = blockIdx.z;
  const int i = zsel(iz, z), b = zsel(bz, z);
  const int m0 = blockIdx.y * 128, n0 = blockIdx.x * 128;
  const int sect = n0 >> 9;  // 0=Q,1=K,2=V
  const unsigned short* chalf = cacheB + (size_t)i * SD;
  const unsigned short* hsrc = (i == 0) ? xB + (size_t)b * SD : cacheB + (size_t)(i - 1) * SD;
  const unsigned short* qsrc = gB + (size_t)b * SD;
  const unsigned short* W = Wt + (size_t)i * 1536 * 1024;
  const int tid = threadIdx.x, lane = tid & 63, w = tid >> 6;
  const int lr = lane & 15, lg = lane >> 4;
  const int wrow = (w >> 1) * 64, wcol = (w & 1) * 64;
  f32x4 acc[4][4] = {};
  for (int kt = 0; kt < 1024; kt += 64) {
    const unsigned short* Asrc;
    int ac;
    if (kt < 512) { Asrc = chalf; ac = kt; }
    else { Asrc = (sect == 0) ? qsrc : hsrc; ac = kt - 512; }
    __syncthreads();
    stage_tile(Asrc, 512, m0, ac, As, w, lane);
    stage_tile(W, 1024, n0, kt, Bs, w, lane);
    __syncthreads();
    gemm_compute_tile(As, Bs, wrow, wcol, lr, lg, acc);
  }
  const float* bptr = bias + (size_t)i * 1536;
  unsigned short* dstb = (sect == 0 ? Qb2 : sect == 1 ? Kb2 : Vb2) + (size_t)i * SD;
  float* dstf = (sect == 0) ? Qf + (size_t)i * SD : nullptr;
#pragma unroll
  for (int mi = 0; mi < 4; ++mi)
#pragma unroll
    for (int ni = 0; ni < 4; ++ni) {
      int fc = n0 + wcol + ni * 16 + lr;
      int lc = fc & 511;
      float bv = bptr[fc];
#pragma unroll
      for (int r = 0; r < 4; ++r) {
        int row = m0 + wrow + mi * 16 + lg * 4 + r;
        float v = acc[mi][ni][r] + bv;
        dstb[(size_t)row * 512 + lc] = f2bf(v);
        if (dstf) dstf[(size_t)row * 512 + lc] = v;
      }
    }
}

// Generic GEMM: C[2048][N] = A[2048][K] @ Wt[N][K]^T + bias, bf16 out.
template<int RELU>
__global__ __launch_bounds__(256) void gemm_gen(
    const unsigned short* __restrict__ Abase, size_t aStride,
    const unsigned short* __restrict__ Wbase, const float* __restrict__ biasBase,
    unsigned short* __restrict__ Cbase, size_t cStride,
    int N, int K, int4 iz) {
  __shared__ __align__(16) unsigned short As[128 * 64];
  __shared__ __align__(16) unsigned short Bs[128 * 64];
  const int z = blockIdx.z;
  const int i = zsel(iz, z);
  const unsigned short* A = Abase + (size_t)i * aStride;
  const unsigned short* W = Wbase + (size_t)i * N * K;
  const float* bias = biasBase + (size_t)i * N;
  unsigned short* C = Cbase + (size_t)i * cStride;
  const int m0 = blockIdx.y * 128, n0 = blockIdx.x * 128;
  const int tid = threadIdx.x, lane = tid & 63, w = tid >> 6;
  const int lr = lane & 15, lg = lane >> 4;
  const int wrow = (w >> 1) * 64, wcol = (w & 1) * 64;
  f32x4 acc[4][4] = {};
  for (int kt = 0; kt < K; kt += 64) {
    __syncthreads();
    stage_tile(A, K, m0, kt, As, w, lane);
    stage_tile(W, K, n0, kt, Bs, w, lane);
    __syncthreads();
    gemm_compute_tile(As, Bs, wrow, wcol, lr, lg, acc);
  }
#pragma unroll
  for (int mi = 0; mi < 4; ++mi)
#pragma unroll
    for (int ni = 0; ni < 4; ++ni) {
      int col = n0 + wcol + ni * 16 + lr;
      float bv = bias[col];
#pragma unroll
      for (int r = 0; r < 4; ++r) {
        int row = m0 + wrow + mi * 16 + lg * 4 + r;
        float v = acc[mi][ni][r] + bv;
        if (RELU) v = fmaxf(v, 0.f);
        C[(size_t)row * N + col] = f2bf(v);
      }
    }
}

// Flash attention: block = (64 q-rows, head, z). 4 waves, each 16 q-rows.
__global__ __launch_bounds__(256) void attn_kernel(const unsigned short* __restrict__ Qb,
                                                   const unsigned short* __restrict__ Kb,
                                                   const unsigned short* __restrict__ Vb,
                                                   unsigned short* __restrict__ Oa, int4 iz) {
  __shared__ __align__(16) unsigned short Ks[64][72];
  __shared__ __align__(16) unsigned short VT[64][72];
  __shared__ __align__(16) unsigned short Pl[4][16][72];
  const int i = zsel(iz, blockIdx.z);
  Qb += (size_t)i * SD; Kb += (size_t)i * SD; Vb += (size_t)i * SD; Oa += (size_t)i * SD;
  const int tid = threadIdx.x, lane = tid & 63, w = tid >> 6;
  const int lr = lane & 15, lg = lane >> 4;
  const int h = blockIdx.y;
  const int q0 = blockIdx.x * 64;
  const int qrow = q0 + w * 16 + lr;
  bf16x8 aq0 = *(const bf16x8*)(Qb + (size_t)qrow * Dn + h * 64 + lg * 8);
  bf16x8 aq1 = *(const bf16x8*)(Qb + (size_t)qrow * Dn + h * 64 + 32 + lg * 8);
  f32x4 o[4] = {};
  float mrow[4] = {-3e38f, -3e38f, -3e38f, -3e38f};
  float lrow[4] = {0.f, 0.f, 0.f, 0.f};
  for (int kt = 0; kt < Sn; kt += 64) {
    __syncthreads();
#pragma unroll
    for (int half = 0; half < 2; ++half) {
      int idx = tid + half * 256;
      int key = idx >> 3, d0 = (idx & 7) << 3;
      *(uint4*)&Ks[key][d0] = *(const uint4*)(Kb + (size_t)(kt + key) * Dn + h * 64 + d0);
      uint4 uv = *(const uint4*)(Vb + (size_t)(kt + key) * Dn + h * 64 + d0);
      us8v v8 = __builtin_bit_cast(us8v, uv);
#pragma unroll
      for (int j = 0; j < 8; ++j) VT[d0 + j][key] = v8[j];
    }
    __syncthreads();
    f32x4 s[4];
#pragma unroll
    for (int nb = 0; nb < 4; ++nb) {
      bf16x8 bk0 = *(const bf16x8*)&Ks[lr + 16 * nb][lg * 8];
      bf16x8 bk1 = *(const bf16x8*)&Ks[lr + 16 * nb][32 + lg * 8];
      f32x4 zz = {};
      zz = mfma_bf16(aq0, bk0, zz);
      zz = mfma_bf16(aq1, bk1, zz);
      s[nb] = zz;
    }
#pragma unroll
    for (int r = 0; r < 4; ++r) {
      float mx = -3e38f;
#pragma unroll
      for (int nb = 0; nb < 4; ++nb) { s[nb][r] *= 0.125f; mx = fmaxf(mx, s[nb][r]); }
      mx = fmaxf(mx, __shfl_xor(mx, 1));
      mx = fmaxf(mx, __shfl_xor(mx, 2));
      mx = fmaxf(mx, __shfl_xor(mx, 4));
      mx = fmaxf(mx, __shfl_xor(mx, 8));
      float mnew = fmaxf(mrow[r], mx);
      float resc = __expf(mrow[r] - mnew);
      float ps = 0.f;
#pragma unroll
      for (int nb = 0; nb < 4; ++nb) { float p = __expf(s[nb][r] - mnew); s[nb][r] = p; ps += p; }
      ps += __shfl_xor(ps, 1);
      ps += __shfl_xor(ps, 2);
      ps += __shfl_xor(ps, 4);
      ps += __shfl_xor(ps, 8);
      lrow[r] = lrow[r] * resc + ps;
      mrow[r] = mnew;
#pragma unroll
      for (int nb = 0; nb < 4; ++nb) o[nb][r] *= resc;
    }
#pragma unroll
    for (int nb = 0; nb < 4; ++nb)
#pragma unroll
      for (int r = 0; r < 4; ++r)
        Pl[w][lg * 4 + r][lr + 16 * nb] = f2bf(s[nb][r]);
    __syncthreads();
    bf16x8 ap0 = *(const bf16x8*)&Pl[w][lr][lg * 8];
    bf16x8 ap1 = *(const bf16x8*)&Pl[w][lr][32 + lg * 8];
#pragma unroll
    for (int nb = 0; nb < 4; ++nb) {
      bf16x8 bv0 = *(const bf16x8*)&VT[lr + 16 * nb][lg * 8];
      bf16x8 bv1 = *(const bf16x8*)&VT[lr + 16 * nb][32 + lg * 8];
      o[nb] = mfma_bf16(ap0, bv0, o[nb]);
      o[nb] = mfma_bf16(ap1, bv1, o[nb]);
    }
  }
#pragma unroll
  for (int nb = 0; nb < 4; ++nb)
#pragma unroll
    for (int r = 0; r < 4; ++r) {
      int row = q0 + w * 16 + lg * 4 + r;
      int col = h * 64 + lr + 16 * nb;
      Oa[(size_t)row * Dn + col] = f2bf(o[nb][r] / lrow[r]);
    }
}

// LN1: y = ln(bf16 O2 + f32 Qf) -> yf f32, yb bf16
__global__ __launch_bounds__(256) void ln1_kernel(const unsigned short* __restrict__ O2,
                                                  const float* __restrict__ Qf,
                                                  const float* __restrict__ gam, const float* __restrict__ bet,
                                                  float* __restrict__ yf, unsigned short* __restrict__ yb,
                                                  int4 iz) {
  const int z = blockIdx.y, i = zsel(iz, z);
  const int w = threadIdx.x >> 6, lane = threadIdx.x & 63;
  const int row = blockIdx.x * 4 + w;
  const size_t base = (size_t)i * SD + (size_t)row * Dn + lane * 8;
  us8v av = *(const us8v*)(O2 + base);
  float4 b0 = *(const float4*)(Qf + base);
  float4 b1 = *(const float4*)(Qf + base + 4);
  float x[8];
  x[0] = bf2f(av[0]) + b0.x; x[1] = bf2f(av[1]) + b0.y;
  x[2] = bf2f(av[2]) + b0.z; x[3] = bf2f(av[3]) + b0.w;
  x[4] = bf2f(av[4]) + b1.x; x[5] = bf2f(av[5]) + b1.y;
  x[6] = bf2f(av[6]) + b1.z; x[7] = bf2f(av[7]) + b1.w;
  float sm = 0.f;
#pragma unroll
  for (int j = 0; j < 8; ++j) sm += x[j];
#pragma unroll
  for (int msk = 1; msk < 64; msk <<= 1) sm += __shfl_xor(sm, msk);
  float mean = sm * (1.f / Dn);
  float vs = 0.f;
#pragma unroll
  for (int j = 0; j < 8; ++j) { float d = x[j] - mean; vs += d * d; }
#pragma unroll
  for (int msk = 1; msk < 64; msk <<= 1) vs += __shfl_xor(vs, msk);
  float rs = rsqrtf(vs * (1.f / Dn) + EPSc);
  const int col0 = lane * 8;
  const float* gp = gam + (size_t)i * Dn;
  const float* bp = bet + (size_t)i * Dn;
  float y[8];
#pragma unroll
  for (int j = 0; j < 8; ++j) y[j] = gp[col0 + j] * ((x[j] - mean) * rs) + bp[col0 + j];
  *(float4*)(yf + base) = make_float4(y[0], y[1], y[2], y[3]);
  *(float4*)(yf + base + 4) = make_float4(y[4], y[5], y[6], y[7]);
  us8v p = {f2bf(y[0]), f2bf(y[1]), f2bf(y[2]), f2bf(y[3]),
            f2bf(y[4]), f2bf(y[5]), f2bf(y[6]), f2bf(y[7])};
  *(us8v*)(yb + base) = p;
}

// LN2: h = ln(f32 yf + bf16 f2) -> cacheB bf16 (always) + out f32 (last layer)
__global__ __launch_bounds__(256) void ln2_kernel(const float* __restrict__ yf,
                                                  const unsigned short* __restrict__ f2,
                                                  const float* __restrict__ gam, const float* __restrict__ bet,
                                                  unsigned short* __restrict__ cacheB, float* __restrict__ out,
                                                  int4 iz, int4 bz) {
  const int z = blockIdx.y, i = zsel(iz, z), b = zsel(bz, z);
  const int w = threadIdx.x >> 6, lane = threadIdx.x & 63;
  const int row = blockIdx.x * 4 + w;
  const size_t rbase = (size_t)row * Dn + lane * 8;
  const size_t base = (size_t)i * SD + rbase;
  float4 a0 = *(const float4*)(yf + base);
  float4 a1 = *(const float4*)(yf + base + 4);
  us8v bv = *(const us8v*)(f2 + base);
  float x[8];
  x[0] = a0.x + bf2f(bv[0]); x[1] = a0.y + bf2f(bv[1]);
  x[2] = a0.z + bf2f(bv[2]); x[3] = a0.w + bf2f(bv[3]);
  x[4] = a1.x + bf2f(bv[4]); x[5] = a1.y + bf2f(bv[5]);
  x[6] = a1.z + bf2f(bv[6]); x[7] = a1.w + bf2f(bv[7]);
  float sm = 0.f;
#pragma unroll
  for (int j = 0; j < 8; ++j) sm += x[j];
#pragma unroll
  for (int msk = 1; msk < 64; msk <<= 1) sm += __shfl_xor(sm, msk);
  float mean = sm * (1.f / Dn);
  float vs = 0.f;
#pragma unroll
  for (int j = 0; j < 8; ++j) { float d = x[j] - mean; vs += d * d; }
#pragma unroll
  for (int msk = 1; msk < 64; msk <<= 1) vs += __shfl_xor(vs, msk);
  float rs = rsqrtf(vs * (1.f / Dn) + EPSc);
  const int col0 = lane * 8;
  const float* gp = gam + (size_t)i * Dn;
  const float* bp = bet + (size_t)i * Dn;
  float y[8];
#pragma unroll
  for (int j = 0; j < 8; ++j) y[j] = gp[col0 + j] * ((x[j] - mean) * rs) + bp[col0 + j];
  us8v p = {f2bf(y[0]), f2bf(y[1]), f2bf(y[2]), f2bf(y[3]),
            f2bf(y[4]), f2bf(y[5]), f2bf(y[6]), f2bf(y[7])};
  *(us8v*)(cacheB + base) = p;
  if (i == Ln - 1) {
    float* op = out + (size_t)b * SD + rbase;
    *(float4*)op = make_float4(y[0], y[1], y[2], y[3]);
    *(float4*)(op + 4) = make_float4(y[4], y[5], y[6], y[7]);
  }
}

extern "C" void kernel_launch(void* const* d_in, const int* in_sizes, int n_in,
                              void* d_out, int out_size, void* d_ws, size_t ws_size,
                              hipStream_t stream) {
  (void)in_sizes; (void)n_in; (void)out_size; (void)ws_size;
  const float* x   = (const float*)d_in[0];
  const float* gq  = (const float*)d_in[1];
  const float* WQw = (const float*)d_in[2];
  const float* WQb = (const float*)d_in[3];
  const float* WKw = (const float*)d_in[4];
  const float* WKb = (const float*)d_in[5];
  const float* WVw = (const float*)d_in[6];
  const float* WVb = (const float*)d_in[7];
  const float* WOw = (const float*)d_in[8];
  const float* WOb = (const float*)d_in[9];
  const float* l1g = (const float*)d_in[10];
  const float* l1b = (const float*)d_in[11];
  const float* W1  = (const float*)d_in[12];
  const float* b1  = (const float*)d_in[13];
  const float* W2  = (const float*)d_in[14];
  const float* b2  = (const float*)d_in[15];
  const float* l2g = (const float*)d_in[16];
  const float* l2b = (const float*)d_in[17];
  float* out = (float*)d_out;

  char* wsp = (char*)d_ws;
  size_t off = 0;
  auto alloc = [&](size_t bytes) -> void* {
    void* p = wsp + off;
    off += (bytes + 255) & ~(size_t)255;
    return p;
  };

  unsigned short* cacheB = (unsigned short*)alloc(Ln * SD * 2);
  unsigned short* xB = (unsigned short*)alloc(Bn * SD * 2);
  unsigned short* gB = (unsigned short*)alloc(Bn * SD * 2);
  float*          Qf  = (float*)alloc(Ln * SD * 4);
  unsigned short* Qb2 = (unsigned short*)alloc(Ln * SD * 2);
  unsigned short* Kb2 = (unsigned short*)alloc(Ln * SD * 2);
  unsigned short* Vb2 = (unsigned short*)alloc(Ln * SD * 2);
  unsigned short* Oa  = (unsigned short*)alloc(Ln * SD * 2);
  unsigned short* O2  = (unsigned short*)alloc(Ln * SD * 2);
  float*          yf  = (float*)alloc(Ln * SD * 4);
  unsigned short* yb  = (unsigned short*)alloc(Ln * SD * 2);
  unsigned short* f2  = (unsigned short*)alloc(Ln * SD * 2);
  unsigned short* f1  = (unsigned short*)alloc(Ln * SM * 2);
  unsigned short* WQKVt = (unsigned short*)alloc((size_t)Ln * 1536 * 1024 * 2);
  unsigned short* WOt = (unsigned short*)alloc((size_t)Ln * 512 * 512 * 2);
  unsigned short* W1t = (unsigned short*)alloc((size_t)Ln * 2048 * 512 * 2);
  unsigned short* W2t = (unsigned short*)alloc((size_t)Ln * 512 * 2048 * 2);
  float* qkvB = (float*)alloc((size_t)Ln * 1536 * 4);

  hipMemsetAsync(cacheB, 0, Ln * SD * 2, stream);

  // One-time conversions / transposes
  cvt_bf16<<<Bn * SD / 8 / 256, 256, 0, stream>>>(x, xB);
  cvt_bf16<<<Bn * SD / 8 / 256, 256, 0, stream>>>(gq, gB);
  dim3 tb(32, 8);
  transpose_convert<<<dim3(16, 32, Ln), tb, 0, stream>>>(WQw, WQKVt, 1024, 512,
                                                         (size_t)1024 * 512, (size_t)1536 * 1024);
  transpose_convert<<<dim3(16, 32, Ln), tb, 0, stream>>>(WKw, WQKVt + (size_t)512 * 1024, 1024, 512,
                                                         (size_t)1024 * 512, (size_t)1536 * 1024);
  transpose_convert<<<dim3(16, 32, Ln), tb, 0, stream>>>(WVw, WQKVt + (size_t)1024 * 1024, 1024, 512,
                                                         (size_t)1024 * 512, (size_t)1536 * 1024);
  transpose_convert<<<dim3(16, 16, Ln), tb, 0, stream>>>(WOw, WOt, 512, 512,
                                                         (size_t)512 * 512, (size_t)512 * 512);
  transpose_convert<<<dim3(64, 16, Ln), tb, 0, stream>>>(W1, W1t, 512, 2048,
                                                         (size_t)512 * 2048, (size_t)2048 * 512);
  transpose_convert<<<dim3(16, 64, Ln), tb, 0, stream>>>(W2, W2t, 2048, 512,
                                                         (size_t)2048 * 512, (size_t)512 * 2048);
  fuse_bias<<<Ln * 1536 / 256, 256, 0, stream>>>(WQb, WKb, WVb, qkvB);

  // Diagonal wavefront: steps (b, i) with b+i == d are independent.
  for (int d = 0; d < Bn + Ln - 1; ++d) {
    int izv[4] = {0, 0, 0, 0}, bzv[4] = {0, 0, 0, 0};
    int nz = 0;
    int blo = d > Ln - 1 ? d - Ln + 1 : 0;
    int bhi = d < Bn - 1 ? d : Bn - 1;
    for (int b = blo; b <= bhi; ++b) { izv[nz] = d - b; bzv[nz] = b; ++nz; }
    int4 iz = {izv[0], izv[1], izv[2], izv[3]};
    int4 bz = {bzv[0], bzv[1], bzv[2], bzv[3]};

    gemm_qkv<<<dim3(12, 16, nz), 256, 0, stream>>>(cacheB, xB, gB, WQKVt, qkvB,
                                                   Qb2, Qf, Kb2, Vb2, iz, bz);
    attn_kernel<<<dim3(32, 8, nz), 256, 0, stream>>>(Qb2, Kb2, Vb2, Oa, iz);
    gemm_gen<0><<<dim3(4, 16, nz), 256, 0, stream>>>(Oa, SD, WOt, WOb, O2, SD, 512, 512, iz);
    ln1_kernel<<<dim3(512, nz), 256, 0, stream>>>(O2, Qf, l1g, l1b, yf, yb, iz);
    gemm_gen<1><<<dim3(16, 16, nz), 256, 0, stream>>>(yb, SD, W1t, b1, f1, SM, 2048, 512, iz);
    gemm_gen<0><<<dim3(4, 16, nz), 256, 0, stream>>>(f1, SM, W2t, b2, f2, SD, 512, 2048, iz);
    ln2_kernel<<<dim3(512, nz), 256, 0, stream>>>(yf, f2, l2g, l2b, cacheB, out, iz, bz);
  }
}

// Round 4
// 2443.162 us; speedup vs baseline: 3.2149x; 1.2590x over previous
//
#include <hip/hip_runtime.h>
#include <cstddef>

#define Bn 8
#define Sn 2048
#define Dn 512
#define Ln 4
#define Hn 8
#define Mn 2048
#define EPSc 1e-3f
static const size_t SD = (size_t)Sn * Dn;
static const size_t SM = (size_t)Sn * Mn;

typedef __bf16 bf16x8 __attribute__((ext_vector_type(8)));
typedef float f32x4 __attribute__((ext_vector_type(4)));
typedef unsigned short us8v __attribute__((ext_vector_type(8)));
typedef unsigned short us4v __attribute__((ext_vector_type(4)));
typedef unsigned int u32;

static __device__ __forceinline__ unsigned short f2bf(float f) {
  u32 u = __builtin_bit_cast(u32, f);
  u = u + 0x7fffu + ((u >> 16) & 1u);
  return (unsigned short)(u >> 16);
}
static __device__ __forceinline__ float bf2f(unsigned short u) {
  return __builtin_bit_cast(float, (u32)u << 16);
}
static __device__ __forceinline__ f32x4 mfma_bf16(bf16x8 a, bf16x8 b, f32x4 c) {
  return __builtin_amdgcn_mfma_f32_16x16x32_bf16(a, b, c, 0, 0, 0);
}
static __device__ __forceinline__ int zsel(int4 v, int z) {
  return z == 0 ? v.x : z == 1 ? v.y : z == 2 ? v.z : v.w;
}
static __device__ __forceinline__ void gload16(const unsigned short* g, unsigned short* l) {
  __builtin_amdgcn_global_load_lds((const __attribute__((address_space(1))) u32*)(const void*)g,
                                   (__attribute__((address_space(3))) u32*)(void*)l, 16, 0, 0);
}

// Stage a 128x64 bf16 tile: linear LDS dest, inverse-swizzled global source.
static __device__ __forceinline__ void stage_tile(const unsigned short* __restrict__ src, int lda,
                                                  int row0, int col0,
                                                  unsigned short* lds, int w, int lane) {
#pragma unroll
  for (int r = 0; r < 4; ++r) {
    int c = (w * 4 + r) * 64 + lane;
    int row = c >> 3, cc = c & 7;
    int scc = cc ^ (row & 7);
    gload16(src + (size_t)(row0 + row) * lda + col0 + scc * 8, lds + (w * 4 + r) * 64 * 8);
  }
}

// Swizzled fragment reads + 32 MFMAs for one 128x128x64 step.
static __device__ __forceinline__ void gemm_compute_tile(const unsigned short* As, const unsigned short* Bs,
                                                         int wrow, int wcol, int lr, int lg,
                                                         f32x4 acc[4][4]) {
#pragma unroll
  for (int kk = 0; kk < 2; ++kk) {
    bf16x8 af[4], bfr[4];
#pragma unroll
    for (int mi = 0; mi < 4; ++mi) {
      int ra = wrow + mi * 16 + lr;
      af[mi] = *(const bf16x8*)&As[ra * 64 + ((kk * 4 + lg) ^ (ra & 7)) * 8];
      int rb = wcol + mi * 16 + lr;
      bfr[mi] = *(const bf16x8*)&Bs[rb * 64 + ((kk * 4 + lg) ^ (rb & 7)) * 8];
    }
#pragma unroll
    for (int ni = 0; ni < 4; ++ni)
#pragma unroll
      for (int mi = 0; mi < 4; ++mi)
        acc[mi][ni] = mfma_bf16(af[mi], bfr[ni], acc[mi][ni]);
  }
}

// in: f32 [Z][R][C] -> out: bf16 [Z][C][R]
__global__ void transpose_convert(const float* __restrict__ in, unsigned short* __restrict__ outT,
                                  int R, int C, size_t inZ, size_t outZ) {
  __shared__ float tile[32][33];
  in += (size_t)blockIdx.z * inZ;
  outT += (size_t)blockIdx.z * outZ;
  int c0 = blockIdx.x * 32, r0 = blockIdx.y * 32;
  for (int i = threadIdx.y; i < 32; i += 8)
    tile[i][threadIdx.x] = in[(size_t)(r0 + i) * C + c0 + threadIdx.x];
  __syncthreads();
  for (int i = threadIdx.y; i < 32; i += 8)
    outT[(size_t)(c0 + i) * R + r0 + threadIdx.x] = f2bf(tile[threadIdx.x][i]);
}

__global__ void cvt_bf16(const float* __restrict__ in, unsigned short* __restrict__ out) {
  size_t idx = ((size_t)blockIdx.x * 256 + threadIdx.x) * 8;
  float4 a = *(const float4*)(in + idx);
  float4 b = *(const float4*)(in + idx + 4);
  us8v p = {f2bf(a.x), f2bf(a.y), f2bf(a.z), f2bf(a.w), f2bf(b.x), f2bf(b.y), f2bf(b.z), f2bf(b.w)};
  *(us8v*)(out + idx) = p;
}

__global__ void fuse_bias(const float* __restrict__ q, const float* __restrict__ k,
                          const float* __restrict__ v, float* __restrict__ o) {
  int t = blockIdx.x * 256 + threadIdx.x;  // over Ln*1536
  int l = t / 1536, n = t % 1536;
  float val = n < 512 ? q[l * 512 + n] : n < 1024 ? k[l * 512 + n - 512] : v[l * 512 + n - 1024];
  o[t] = val;
}

// Fused QKV GEMM: C[2048][1536] over K=1024 (concat inputs selected per K-tile).
__global__ __launch_bounds__(256) void gemm_qkv(
    const unsigned short* __restrict__ cacheB, const unsigned short* __restrict__ xB,
    const unsigned short* __restrict__ gB,
    const unsigned short* __restrict__ Wt, const float* __restrict__ bias,
    unsigned short* __restrict__ Qb2, float* __restrict__ Qf,
    unsigned short* __restrict__ Kb2, unsigned short* __restrict__ Vb2,
    int4 iz, int4 bz) {
  __shared__ __align__(16) unsigned short As[128 * 64];
  __shared__ __align__(16) unsigned short Bs[128 * 64];
  const int z = blockIdx.z;
  const int i = zsel(iz, z), b = zsel(bz, z);
  const int m0 = blockIdx.y * 128, n0 = blockIdx.x * 128;
  const int sect = n0 >> 9;  // 0=Q,1=K,2=V
  const unsigned short* chalf = cacheB + (size_t)i * SD;
  const unsigned short* hsrc = (i == 0) ? xB + (size_t)b * SD : cacheB + (size_t)(i - 1) * SD;
  const unsigned short* qsrc = gB + (size_t)b * SD;
  const unsigned short* W = Wt + (size_t)i * 1536 * 1024;
  const int tid = threadIdx.x, lane = tid & 63, w = tid >> 6;
  const int lr = lane & 15, lg = lane >> 4;
  const int wrow = (w >> 1) * 64, wcol = (w & 1) * 64;
  f32x4 acc[4][4] = {};
  for (int kt = 0; kt < 1024; kt += 64) {
    const unsigned short* Asrc;
    int ac;
    if (kt < 512) { Asrc = chalf; ac = kt; }
    else { Asrc = (sect == 0) ? qsrc : hsrc; ac = kt - 512; }
    __syncthreads();
    stage_tile(Asrc, 512, m0, ac, As, w, lane);
    stage_tile(W, 1024, n0, kt, Bs, w, lane);
    __syncthreads();
    gemm_compute_tile(As, Bs, wrow, wcol, lr, lg, acc);
  }
  const float* bptr = bias + (size_t)i * 1536;
  unsigned short* dstb = (sect == 0 ? Qb2 : sect == 1 ? Kb2 : Vb2) + (size_t)i * SD;
  float* dstf = (sect == 0) ? Qf + (size_t)i * SD : nullptr;
#pragma unroll
  for (int mi = 0; mi < 4; ++mi)
#pragma unroll
    for (int ni = 0; ni < 4; ++ni) {
      int fc = n0 + wcol + ni * 16 + lr;
      int lc = fc & 511;
      float bv = bptr[fc];
#pragma unroll
      for (int r = 0; r < 4; ++r) {
        int row = m0 + wrow + mi * 16 + lg * 4 + r;
        float v = acc[mi][ni][r] + bv;
        dstb[(size_t)row * 512 + lc] = f2bf(v);
        if (dstf) dstf[(size_t)row * 512 + lc] = v;
      }
    }
}

// Generic GEMM: C[2048][N] = A[2048][K] @ Wt[N][K]^T + bias, bf16 out.
template<int RELU>
__global__ __launch_bounds__(256) void gemm_gen(
    const unsigned short* __restrict__ Abase, size_t aStride,
    const unsigned short* __restrict__ Wbase, const float* __restrict__ biasBase,
    unsigned short* __restrict__ Cbase, size_t cStride,
    int N, int K, int4 iz) {
  __shared__ __align__(16) unsigned short As[128 * 64];
  __shared__ __align__(16) unsigned short Bs[128 * 64];
  const int z = blockIdx.z;
  const int i = zsel(iz, z);
  const unsigned short* A = Abase + (size_t)i * aStride;
  const unsigned short* W = Wbase + (size_t)i * N * K;
  const float* bias = biasBase + (size_t)i * N;
  unsigned short* C = Cbase + (size_t)i * cStride;
  const int m0 = blockIdx.y * 128, n0 = blockIdx.x * 128;
  const int tid = threadIdx.x, lane = tid & 63, w = tid >> 6;
  const int lr = lane & 15, lg = lane >> 4;
  const int wrow = (w >> 1) * 64, wcol = (w & 1) * 64;
  f32x4 acc[4][4] = {};
  for (int kt = 0; kt < K; kt += 64) {
    __syncthreads();
    stage_tile(A, K, m0, kt, As, w, lane);
    stage_tile(W, K, n0, kt, Bs, w, lane);
    __syncthreads();
    gemm_compute_tile(As, Bs, wrow, wcol, lr, lg, acc);
  }
#pragma unroll
  for (int mi = 0; mi < 4; ++mi)
#pragma unroll
    for (int ni = 0; ni < 4; ++ni) {
      int col = n0 + wcol + ni * 16 + lr;
      float bv = bias[col];
#pragma unroll
      for (int r = 0; r < 4; ++r) {
        int row = m0 + wrow + mi * 16 + lg * 4 + r;
        float v = acc[mi][ni][r] + bv;
        if (RELU) v = fmaxf(v, 0.f);
        C[(size_t)row * N + col] = f2bf(v);
      }
    }
}

// Flash attention, swapped-QK^T in-register-P version.
// block = (64 q-rows, head, z); 4 waves, each 16 q-rows (q = lr).
__global__ __launch_bounds__(256) void attn_kernel(const unsigned short* __restrict__ Qb,
                                                   const unsigned short* __restrict__ Kb,
                                                   const unsigned short* __restrict__ Vb,
                                                   unsigned short* __restrict__ Oa, int4 iz) {
  __shared__ __align__(16) unsigned short Ks[64 * 64];
  __shared__ __align__(16) unsigned short VT[64 * 64];
  const int i = zsel(iz, blockIdx.z);
  Qb += (size_t)i * SD; Kb += (size_t)i * SD; Vb += (size_t)i * SD; Oa += (size_t)i * SD;
  const int tid = threadIdx.x, lane = tid & 63, w = tid >> 6;
  const int lr = lane & 15, lg = lane >> 4;
  const int h = blockIdx.y;
  const int q0 = blockIdx.x * 64;
  const int qrow = q0 + w * 16 + lr;
  // Q fragment: B-operand rows q=lr, d-slots (lg,j) <-> d = lg*8+j (+32)
  bf16x8 aq0 = *(const bf16x8*)(Qb + (size_t)qrow * Dn + h * 64 + lg * 8);
  bf16x8 aq1 = *(const bf16x8*)(Qb + (size_t)qrow * Dn + h * 64 + 32 + lg * 8);
  f32x4 o[4] = {};
  float mrow = -3e38f, lrow = 0.f;
  for (int kt = 0; kt < Sn; kt += 64) {
    __syncthreads();
    // K: async gload, XOR-chunk swizzled (LDS chunk (row,cc) holds global chunk cc^(row&7))
#pragma unroll
    for (int rr = 0; rr < 2; ++rr) {
      int a = (w * 2 + rr) * 64 + lane;
      int row = a >> 3, cc = a & 7;
      gload16(Kb + (size_t)(kt + row) * Dn + h * 64 + ((cc ^ (row & 7)) << 3),
              Ks + (w * 2 + rr) * 512);
    }
    // V: per-lane-row load + swizzled transpose scatter (conflict-free: 64 cols/instr)
#pragma unroll
    for (int u = 0; u < 2; ++u) {
      int d0 = w * 16 + u * 8;
      uint4 uv = *(const uint4*)(Vb + (size_t)(kt + lane) * Dn + h * 64 + d0);
      us8v v8 = __builtin_bit_cast(us8v, uv);
#pragma unroll
      for (int j = 0; j < 8; ++j) {
        int c = d0 + j;
        VT[c * 64 + (((lane >> 3) ^ (c & 7)) << 3) + (lane & 7)] = v8[j];
      }
    }
    __syncthreads();
    // QK^T swapped: s[kb][r] = S[key=16kb+lg*4+r][q=lr]
    f32x4 s[4];
    __builtin_amdgcn_s_setprio(1);
#pragma unroll
    for (int kb = 0; kb < 4; ++kb) {
      int krow = kb * 16 + lr;
      bf16x8 k0 = *(const bf16x8*)&Ks[krow * 64 + ((lg ^ (krow & 7)) << 3)];
      bf16x8 k1 = *(const bf16x8*)&Ks[krow * 64 + (((4 + lg) ^ (krow & 7)) << 3)];
      f32x4 zz = {};
      zz = mfma_bf16(k0, aq0, zz);
      zz = mfma_bf16(k1, aq1, zz);
      s[kb] = zz;
    }
    __builtin_amdgcn_s_setprio(0);
    // online softmax over 64 keys (per lane: q = lr); scale folded into exp
    float mx = -3e38f;
#pragma unroll
    for (int kb = 0; kb < 4; ++kb)
#pragma unroll
      for (int r = 0; r < 4; ++r) mx = fmaxf(mx, s[kb][r]);
    mx = fmaxf(mx, __shfl_xor(mx, 16));
    mx = fmaxf(mx, __shfl_xor(mx, 32));
    float mnew = fmaxf(mrow, mx);
    float resc = __expf((mrow - mnew) * 0.125f);
    float mn8 = mnew * 0.125f;
    float ps = 0.f;
    u32 pk[4][2];
#pragma unroll
    for (int kb = 0; kb < 4; ++kb) {
      float p0 = __expf(s[kb][0] * 0.125f - mn8);
      float p1 = __expf(s[kb][1] * 0.125f - mn8);
      float p2 = __expf(s[kb][2] * 0.125f - mn8);
      float p3 = __expf(s[kb][3] * 0.125f - mn8);
      ps += (p0 + p1) + (p2 + p3);
      pk[kb][0] = (u32)f2bf(p0) | ((u32)f2bf(p1) << 16);
      pk[kb][1] = (u32)f2bf(p2) | ((u32)f2bf(p3) << 16);
    }
    ps += __shfl_xor(ps, 16);
    ps += __shfl_xor(ps, 32);
    lrow = lrow * resc + ps;
    mrow = mnew;
    // rescale accumulators: output rows live at q = lg*4+r, stats at lane q=lr
    float rq[4];
#pragma unroll
    for (int r = 0; r < 4; ++r) rq[r] = __shfl(resc, lg * 4 + r);
#pragma unroll
    for (int cb = 0; cb < 4; ++cb)
#pragma unroll
      for (int r = 0; r < 4; ++r) o[cb][r] *= rq[r];
    // PV: A = P (in-register), B = V^T from swizzled VT
    uint4 apw0 = {pk[0][0], pk[0][1], pk[1][0], pk[1][1]};
    uint4 apw1 = {pk[2][0], pk[2][1], pk[3][0], pk[3][1]};
    bf16x8 ap0 = __builtin_bit_cast(bf16x8, apw0);
    bf16x8 ap1 = __builtin_bit_cast(bf16x8, apw1);
    __builtin_amdgcn_s_setprio(1);
#pragma unroll
    for (int cb = 0; cb < 4; ++cb) {
      int c = cb * 16 + lr;
      int cs = c * 64;
      int c7 = c & 7;
      us4v b0a = *(const us4v*)&VT[cs + ((((lg >> 1) + 0) ^ c7) << 3) + (lg & 1) * 4];
      us4v b0b = *(const us4v*)&VT[cs + ((((lg >> 1) + 2) ^ c7) << 3) + (lg & 1) * 4];
      us4v b1a = *(const us4v*)&VT[cs + ((((lg >> 1) + 4) ^ c7) << 3) + (lg & 1) * 4];
      us4v b1b = *(const us4v*)&VT[cs + ((((lg >> 1) + 6) ^ c7) << 3) + (lg & 1) * 4];
      us8v t0 = {b0a[0], b0a[1], b0a[2], b0a[3], b0b[0], b0b[1], b0b[2], b0b[3]};
      us8v t1 = {b1a[0], b1a[1], b1a[2], b1a[3], b1b[0], b1b[1], b1b[2], b1b[3]};
      bf16x8 bv0 = __builtin_bit_cast(bf16x8, t0);
      bf16x8 bv1 = __builtin_bit_cast(bf16x8, t1);
      o[cb] = mfma_bf16(ap0, bv0, o[cb]);
      o[cb] = mfma_bf16(ap1, bv1, o[cb]);
    }
    __builtin_amdgcn_s_setprio(0);
  }
  float lq[4];
#pragma unroll
  for (int r = 0; r < 4; ++r) lq[r] = __shfl(lrow, lg * 4 + r);
#pragma unroll
  for (int cb = 0; cb < 4; ++cb)
#pragma unroll
    for (int r = 0; r < 4; ++r) {
      int row = q0 + w * 16 + lg * 4 + r;
      int col = h * 64 + cb * 16 + lr;
      Oa[(size_t)row * Dn + col] = f2bf(o[cb][r] / lq[r]);
    }
}

// LN1: y = ln(bf16 O2 + f32 Qf) -> yf f32, yb bf16
__global__ __launch_bounds__(256) void ln1_kernel(const unsigned short* __restrict__ O2,
                                                  const float* __restrict__ Qf,
                                                  const float* __restrict__ gam, const float* __restrict__ bet,
                                                  float* __restrict__ yf, unsigned short* __restrict__ yb,
                                                  int4 iz) {
  const int z = blockIdx.y, i = zsel(iz, z);
  const int w = threadIdx.x >> 6, lane = threadIdx.x & 63;
  const int row = blockIdx.x * 4 + w;
  const size_t base = (size_t)i * SD + (size_t)row * Dn + lane * 8;
  us8v av = *(const us8v*)(O2 + base);
  float4 b0 = *(const float4*)(Qf + base);
  float4 b1 = *(const float4*)(Qf + base + 4);
  float x[8];
  x[0] = bf2f(av[0]) + b0.x; x[1] = bf2f(av[1]) + b0.y;
  x[2] = bf2f(av[2]) + b0.z; x[3] = bf2f(av[3]) + b0.w;
  x[4] = bf2f(av[4]) + b1.x; x[5] = bf2f(av[5]) + b1.y;
  x[6] = bf2f(av[6]) + b1.z; x[7] = bf2f(av[7]) + b1.w;
  float sm = 0.f;
#pragma unroll
  for (int j = 0; j < 8; ++j) sm += x[j];
#pragma unroll
  for (int msk = 1; msk < 64; msk <<= 1) sm += __shfl_xor(sm, msk);
  float mean = sm * (1.f / Dn);
  float vs = 0.f;
#pragma unroll
  for (int j = 0; j < 8; ++j) { float d = x[j] - mean; vs += d * d; }
#pragma unroll
  for (int msk = 1; msk < 64; msk <<= 1) vs += __shfl_xor(vs, msk);
  float rs = rsqrtf(vs * (1.f / Dn) + EPSc);
  const int col0 = lane * 8;
  const float* gp = gam + (size_t)i * Dn;
  const float* bp = bet + (size_t)i * Dn;
  float y[8];
#pragma unroll
  for (int j = 0; j < 8; ++j) y[j] = gp[col0 + j] * ((x[j] - mean) * rs) + bp[col0 + j];
  *(float4*)(yf + base) = make_float4(y[0], y[1], y[2], y[3]);
  *(float4*)(yf + base + 4) = make_float4(y[4], y[5], y[6], y[7]);
  us8v p = {f2bf(y[0]), f2bf(y[1]), f2bf(y[2]), f2bf(y[3]),
            f2bf(y[4]), f2bf(y[5]), f2bf(y[6]), f2bf(y[7])};
  *(us8v*)(yb + base) = p;
}

// LN2: h = ln(f32 yf + bf16 f2) -> cacheB bf16 (always) + out f32 (last layer)
__global__ __launch_bounds__(256) void ln2_kernel(const float* __restrict__ yf,
                                                  const unsigned short* __restrict__ f2,
                                                  const float* __restrict__ gam, const float* __restrict__ bet,
                                                  unsigned short* __restrict__ cacheB, float* __restrict__ out,
                                                  int4 iz, int4 bz) {
  const int z = blockIdx.y, i = zsel(iz, z), b = zsel(bz, z);
  const int w = threadIdx.x >> 6, lane = threadIdx.x & 63;
  const int row = blockIdx.x * 4 + w;
  const size_t rbase = (size_t)row * Dn + lane * 8;
  const size_t base = (size_t)i * SD + rbase;
  float4 a0 = *(const float4*)(yf + base);
  float4 a1 = *(const float4*)(yf + base + 4);
  us8v bv = *(const us8v*)(f2 + base);
  float x[8];
  x[0] = a0.x + bf2f(bv[0]); x[1] = a0.y + bf2f(bv[1]);
  x[2] = a0.z + bf2f(bv[2]); x[3] = a0.w + bf2f(bv[3]);
  x[4] = a1.x + bf2f(bv[4]); x[5] = a1.y + bf2f(bv[5]);
  x[6] = a1.z + bf2f(bv[6]); x[7] = a1.w + bf2f(bv[7]);
  float sm = 0.f;
#pragma unroll
  for (int j = 0; j < 8; ++j) sm += x[j];
#pragma unroll
  for (int msk = 1; msk < 64; msk <<= 1) sm += __shfl_xor(sm, msk);
  float mean = sm * (1.f / Dn);
  float vs = 0.f;
#pragma unroll
  for (int j = 0; j < 8; ++j) { float d = x[j] - mean; vs += d * d; }
#pragma unroll
  for (int msk = 1; msk < 64; msk <<= 1) vs += __shfl_xor(vs, msk);
  float rs = rsqrtf(vs * (1.f / Dn) + EPSc);
  const int col0 = lane * 8;
  const float* gp = gam + (size_t)i * Dn;
  const float* bp = bet + (size_t)i * Dn;
  float y[8];
#pragma unroll
  for (int j = 0; j < 8; ++j) y[j] = gp[col0 + j] * ((x[j] - mean) * rs) + bp[col0 + j];
  us8v p = {f2bf(y[0]), f2bf(y[1]), f2bf(y[2]), f2bf(y[3]),
            f2bf(y[4]), f2bf(y[5]), f2bf(y[6]), f2bf(y[7])};
  *(us8v*)(cacheB + base) = p;
  if (i == Ln - 1) {
    float* op = out + (size_t)b * SD + rbase;
    *(float4*)op = make_float4(y[0], y[1], y[2], y[3]);
    *(float4*)(op + 4) = make_float4(y[4], y[5], y[6], y[7]);
  }
}

extern "C" void kernel_launch(void* const* d_in, const int* in_sizes, int n_in,
                              void* d_out, int out_size, void* d_ws, size_t ws_size,
                              hipStream_t stream) {
  (void)in_sizes; (void)n_in; (void)out_size; (void)ws_size;
  const float* x   = (const float*)d_in[0];
  const float* gq  = (const float*)d_in[1];
  const float* WQw = (const float*)d_in[2];
  const float* WQb = (const float*)d_in[3];
  const float* WKw = (const float*)d_in[4];
  const float* WKb = (const float*)d_in[5];
  const float* WVw = (const float*)d_in[6];
  const float* WVb = (const float*)d_in[7];
  const float* WOw = (const float*)d_in[8];
  const float* WOb = (const float*)d_in[9];
  const float* l1g = (const float*)d_in[10];
  const float* l1b = (const float*)d_in[11];
  const float* W1  = (const float*)d_in[12];
  const float* b1  = (const float*)d_in[13];
  const float* W2  = (const float*)d_in[14];
  const float* b2  = (const float*)d_in[15];
  const float* l2g = (const float*)d_in[16];
  const float* l2b = (const float*)d_in[17];
  float* out = (float*)d_out;

  char* wsp = (char*)d_ws;
  size_t off = 0;
  auto alloc = [&](size_t bytes) -> void* {
    void* p = wsp + off;
    off += (bytes + 255) & ~(size_t)255;
    return p;
  };

  unsigned short* cacheB = (unsigned short*)alloc(Ln * SD * 2);
  unsigned short* xB = (unsigned short*)alloc(Bn * SD * 2);
  unsigned short* gB = (unsigned short*)alloc(Bn * SD * 2);
  float*          Qf  = (float*)alloc(Ln * SD * 4);
  unsigned short* Qb2 = (unsigned short*)alloc(Ln * SD * 2);
  unsigned short* Kb2 = (unsigned short*)alloc(Ln * SD * 2);
  unsigned short* Vb2 = (unsigned short*)alloc(Ln * SD * 2);
  unsigned short* Oa  = (unsigned short*)alloc(Ln * SD * 2);
  unsigned short* O2  = (unsigned short*)alloc(Ln * SD * 2);
  float*          yf  = (float*)alloc(Ln * SD * 4);
  unsigned short* yb  = (unsigned short*)alloc(Ln * SD * 2);
  unsigned short* f2  = (unsigned short*)alloc(Ln * SD * 2);
  unsigned short* f1  = (unsigned short*)alloc(Ln * SM * 2);
  unsigned short* WQKVt = (unsigned short*)alloc((size_t)Ln * 1536 * 1024 * 2);
  unsigned short* WOt = (unsigned short*)alloc((size_t)Ln * 512 * 512 * 2);
  unsigned short* W1t = (unsigned short*)alloc((size_t)Ln * 2048 * 512 * 2);
  unsigned short* W2t = (unsigned short*)alloc((size_t)Ln * 512 * 2048 * 2);
  float* qkvB = (float*)alloc((size_t)Ln * 1536 * 4);

  hipMemsetAsync(cacheB, 0, Ln * SD * 2, stream);

  // One-time conversions / transposes
  cvt_bf16<<<Bn * SD / 8 / 256, 256, 0, stream>>>(x, xB);
  cvt_bf16<<<Bn * SD / 8 / 256, 256, 0, stream>>>(gq, gB);
  dim3 tb(32, 8);
  transpose_convert<<<dim3(16, 32, Ln), tb, 0, stream>>>(WQw, WQKVt, 1024, 512,
                                                         (size_t)1024 * 512, (size_t)1536 * 1024);
  transpose_convert<<<dim3(16, 32, Ln), tb, 0, stream>>>(WKw, WQKVt + (size_t)512 * 1024, 1024, 512,
                                                         (size_t)1024 * 512, (size_t)1536 * 1024);
  transpose_convert<<<dim3(16, 32, Ln), tb, 0, stream>>>(WVw, WQKVt + (size_t)1024 * 1024, 1024, 512,
                                                         (size_t)1024 * 512, (size_t)1536 * 1024);
  transpose_convert<<<dim3(16, 16, Ln), tb, 0, stream>>>(WOw, WOt, 512, 512,
                                                         (size_t)512 * 512, (size_t)512 * 512);
  transpose_convert<<<dim3(64, 16, Ln), tb, 0, stream>>>(W1, W1t, 512, 2048,
                                                         (size_t)512 * 2048, (size_t)2048 * 512);
  transpose_convert<<<dim3(16, 64, Ln), tb, 0, stream>>>(W2, W2t, 2048, 512,
                                                         (size_t)2048 * 512, (size_t)512 * 2048);
  fuse_bias<<<Ln * 1536 / 256, 256, 0, stream>>>(WQb, WKb, WVb, qkvB);

  // Diagonal wavefront: steps (b, i) with b+i == d are independent.
  for (int d = 0; d < Bn + Ln - 1; ++d) {
    int izv[4] = {0, 0, 0, 0}, bzv[4] = {0, 0, 0, 0};
    int nz = 0;
    int blo = d > Ln - 1 ? d - Ln + 1 : 0;
    int bhi = d < Bn - 1 ? d : Bn - 1;
    for (int b = blo; b <= bhi; ++b) { izv[nz] = d - b; bzv[nz] = b; ++nz; }
    int4 iz = {izv[0], izv[1], izv[2], izv[3]};
    int4 bz = {bzv[0], bzv[1], bzv[2], bzv[3]};

    gemm_qkv<<<dim3(12, 16, nz), 256, 0, stream>>>(cacheB, xB, gB, WQKVt, qkvB,
                                                   Qb2, Qf, Kb2, Vb2, iz, bz);
    attn_kernel<<<dim3(32, 8, nz), 256, 0, stream>>>(Qb2, Kb2, Vb2, Oa, iz);
    gemm_gen<0><<<dim3(4, 16, nz), 256, 0, stream>>>(Oa, SD, WOt, WOb, O2, SD, 512, 512, iz);
    ln1_kernel<<<dim3(512, nz), 256, 0, stream>>>(O2, Qf, l1g, l1b, yf, yb, iz);
    gemm_gen<1><<<dim3(16, 16, nz), 256, 0, stream>>>(yb, SD, W1t, b1, f1, SM, 2048, 512, iz);
    gemm_gen<0><<<dim3(4, 16, nz), 256, 0, stream>>>(f1, SM, W2t, b2, f2, SD, 512, 2048, iz);
    ln2_kernel<<<dim3(512, nz), 256, 0, stream>>>(yf, f2, l2g, l2b, cacheB, out, iz, bz);
  }
}